// Round 9
// baseline (11444.505 us; speedup 1.0000x reference)
//
#include <hip/hip_runtime.h>
#include <hip/hip_bf16.h>
#include <math.h>

#define VOCAB  32000
#define EMBED  256
#define HIDDEN 512
#define BATCH  32
#define MAXLEN 128
#define NBLK   256            // persistent grid: 1 block per CU (LDS-forced)
#define GBLK   250            // blocks owning a logits v-tile (250*128 = 32000)
#define VB     128            // v-rows per logits block

typedef __attribute__((ext_vector_type(8))) short bf16x8;
typedef __attribute__((ext_vector_type(8))) unsigned short ushort8;
typedef __attribute__((ext_vector_type(4))) float f32x4;

// -------- workspace layout (bytes) --------
#define WS_HHI_OFF   0          // h_hi[2][32][512] bf16             65536
#define WS_HLO_OFF   65536      // h_lo[2][32][512] bf16             65536
#define WS_CAND_OFF  131072     // cand[250][32] u64                 64000
#define WS_CTR_OFF   196608     // stepctr[128][2][64] u32           65536
#define WS_ZERO_BYTES 262144
#define WS_WHI_OFF   262144     // W_hi[32000][512] bf16          32768000
#define WS_WLO_OFF   33030144   // W_lo[32000][512] bf16          32768000

__device__ __forceinline__ unsigned int f32_ordered_key(float f) {
    unsigned int b = __float_as_uint(f);
    return (b & 0x80000000u) ? ~b : (b | 0x80000000u);
}
__device__ __forceinline__ unsigned short f2bf(float x) {
    __hip_bfloat16 h = __float2bfloat16(x);
    return *reinterpret_cast<unsigned short*>(&h);
}
__device__ __forceinline__ float bf2f(unsigned short u) {
    __hip_bfloat16 h = *reinterpret_cast<__hip_bfloat16*>(&u);
    return __bfloat162float(h);
}

// ---------------- W_fc bf16 split precompute (once per launch) ----------------
__global__ __launch_bounds__(256) void split_w_kernel(
    const float* __restrict__ W, unsigned short* __restrict__ hi,
    unsigned short* __restrict__ lo, int n4)
{
    const int stride = gridDim.x * blockDim.x;
    for (int i = blockIdx.x * blockDim.x + threadIdx.x; i < n4; i += stride) {
        f32x4 w = ((const f32x4*)W)[i];
        ushort4 hv, lv;
        #pragma unroll
        for (int j = 0; j < 4; ++j) {
            float x = w[j];
            unsigned short hb = f2bf(x);
            ((unsigned short*)&hv)[j] = hb;
            ((unsigned short*)&lv)[j] = f2bf(x - bf2f(hb));
        }
        ((ushort4*)hi)[i] = hv;
        ((ushort4*)lo)[i] = lv;
    }
}

// ---------------- persistent decoder ----------------
// Per step: A(fold cand->tok, all blocks) ; L(gates+cell, block owns j=2*blk+{0,1},
// c in regs, h->global bf16 hi/lo) ; signal1 ; [blk<GBLK] prefetch W_lo + wait1 ;
// G(logits: W_hi from swizzled LDS, W_lo depth-4 reg stream, h frags from L1/L2,
// 3-pass MFMA identical to r6-r8, nt-store, per-block argmax cand) ; signal2 ; wait2.
// All polls RELAXED + one fence after success (round-8-proven; round-5's acquire-spin
// cache-nuke is the known failure mode to avoid).
#define MFMA(a, b, c) __builtin_amdgcn_mfma_f32_16x16x32_bf16((a), (b), (c), 0, 0, 0)
#define WSPTR(rr, cc) ((const bf16x8*)((const char*)W_s + \
    ((((rr) * 1024) + (cc) * 64 + kg * 16) ^ (((rr) & 7) << 4))))

__global__ __launch_bounds__(512) void decoder_kernel(
    const float* __restrict__ embed,
    const float* __restrict__ W_ih, const float* __restrict__ W_hh,
    const float* __restrict__ b_ih, const float* __restrict__ b_hh,
    const unsigned short* __restrict__ Whi, const unsigned short* __restrict__ Wlo,
    const float* __restrict__ b_fc, float* __restrict__ out,
    unsigned short* __restrict__ h_hi, unsigned short* __restrict__ h_lo,
    unsigned long long* __restrict__ cand, unsigned* __restrict__ stepctr)
{
    __shared__ unsigned short W_s[VB * HIDDEN];          // 128 KB, XOR-swizzled
    __shared__ unsigned long long credl[16][32];         // 4 KB
    __shared__ int tok_s[BATCH];
    __shared__ float part[8 * 32 * 2 * 4];               // 8 KB
    __shared__ float gate_s[2 * 4 * 32];                 // 1 KB
    __shared__ unsigned long long red[8][BATCH];         // 2 KB

    const int tid = threadIdx.x;
    const int blk = blockIdx.x;

    // ---- one-time: stage this block's W_hi tile into swizzled LDS ----
    if (blk < GBLK) {
        const unsigned short* wsrc = Whi + (size_t)blk * VB * HIDDEN;
        #pragma unroll
        for (int i = 0; i < 16; ++i) {
            int u = i * 512 + tid, r = u >> 6, c16 = u & 63;
            int4 v = *(const int4*)(wsrc + (size_t)r * HIDDEN + c16 * 8);
            *(int4*)((char*)W_s + ((r * 1024 + c16 * 16) ^ ((r & 7) << 4))) = v;
        }
    }
    float c_reg = 0.f;     // cell state for (b=tid&31, j=blk*2+(tid>>5)), tid<64
    __syncthreads();

    for (int t = 0; t < MAXLEN; ++t) {
        const int ridx = t & 1, widx = ridx ^ 1;
        unsigned* s1 = stepctr + (size_t)t * 128;
        unsigned* s2 = s1 + 64;

        // ---------- phase A: fold argmax candidates -> tok_s ----------
        if (t > 0) {
            const int rb = tid & 31, seg = tid >> 5;
            unsigned long long m = 0ull;
            for (int i = seg; i < GBLK; i += 16) {
                unsigned long long e = cand[(size_t)i * BATCH + rb];
                if (e > m) m = e;
            }
            credl[seg][rb] = m;
            __syncthreads();
            if (tid < BATCH) {
                unsigned long long mm = credl[0][tid];
                #pragma unroll
                for (int ss = 1; ss < 16; ++ss) if (credl[ss][tid] > mm) mm = credl[ss][tid];
                tok_s[tid] = (int)(~(unsigned int)(mm & 0xFFFFFFFFull));
            }
        } else {
            if (tid < BATCH) tok_s[tid] = 0;
        }
        __syncthreads();

        // ---------- phase L: gates partials (direct global reads) ----------
        {
            const int b = tid & 31, s = (tid >> 5) & 7, jq = tid >> 8;
            const int j = blk * 2 + jq;
            float a0 = 0.f, a1 = 0.f, a2 = 0.f, a3 = 0.f;
            float d0 = 0.f, d1 = 0.f, d2 = 0.f, d3 = 0.f;
            {   // x part: e in [s*32, s*32+32)
                const float4* xr = (const float4*)(embed + (size_t)tok_s[b] * EMBED + s * 32);
                const float4* w0 = (const float4*)(W_ih + (size_t)j * EMBED) + s * 8;
                const float4* w1 = (const float4*)(W_ih + (size_t)(HIDDEN + j) * EMBED) + s * 8;
                const float4* w2 = (const float4*)(W_ih + (size_t)(2 * HIDDEN + j) * EMBED) + s * 8;
                const float4* w3 = (const float4*)(W_ih + (size_t)(3 * HIDDEN + j) * EMBED) + s * 8;
                #pragma unroll
                for (int g = 0; g < 8; ++g) {
                    float4 xv = xr[g];
                    float4 W0 = w0[g], W1 = w1[g], W2 = w2[g], W3 = w3[g];
                    a0 = fmaf(W0.x, xv.x, a0); d0 = fmaf(W0.y, xv.y, d0); a0 = fmaf(W0.z, xv.z, a0); d0 = fmaf(W0.w, xv.w, d0);
                    a1 = fmaf(W1.x, xv.x, a1); d1 = fmaf(W1.y, xv.y, d1); a1 = fmaf(W1.z, xv.z, a1); d1 = fmaf(W1.w, xv.w, d1);
                    a2 = fmaf(W2.x, xv.x, a2); d2 = fmaf(W2.y, xv.y, d2); a2 = fmaf(W2.z, xv.z, a2); d2 = fmaf(W2.w, xv.w, d2);
                    a3 = fmaf(W3.x, xv.x, a3); d3 = fmaf(W3.y, xv.y, d3); a3 = fmaf(W3.z, xv.z, a3); d3 = fmaf(W3.w, xv.w, d3);
                }
            }
            {   // h part: k in [s*64, s*64+64), h = hi + lo
                const ushort8* hr = (const ushort8*)(h_hi + (size_t)ridx * BATCH * HIDDEN + (size_t)b * HIDDEN + s * 64);
                const ushort8* lr = (const ushort8*)(h_lo + (size_t)ridx * BATCH * HIDDEN + (size_t)b * HIDDEN + s * 64);
                const float4* w0 = (const float4*)(W_hh + (size_t)j * HIDDEN) + s * 16;
                const float4* w1 = (const float4*)(W_hh + (size_t)(HIDDEN + j) * HIDDEN) + s * 16;
                const float4* w2 = (const float4*)(W_hh + (size_t)(2 * HIDDEN + j) * HIDDEN) + s * 16;
                const float4* w3 = (const float4*)(W_hh + (size_t)(3 * HIDDEN + j) * HIDDEN) + s * 16;
                #pragma unroll
                for (int i = 0; i < 8; ++i) {
                    ushort8 hv = hr[i], lv = lr[i];
                    float hf[8];
                    #pragma unroll
                    for (int e = 0; e < 8; ++e)
                        hf[e] = bf2f((unsigned short)hv[e]) + bf2f((unsigned short)lv[e]);
                    #pragma unroll
                    for (int q = 0; q < 2; ++q) {
                        float4 W0 = w0[i * 2 + q], W1 = w1[i * 2 + q], W2 = w2[i * 2 + q], W3 = w3[i * 2 + q];
                        float x0 = hf[q * 4 + 0], x1 = hf[q * 4 + 1], x2 = hf[q * 4 + 2], x3 = hf[q * 4 + 3];
                        a0 = fmaf(W0.x, x0, a0); d0 = fmaf(W0.y, x1, d0); a0 = fmaf(W0.z, x2, a0); d0 = fmaf(W0.w, x3, d0);
                        a1 = fmaf(W1.x, x0, a1); d1 = fmaf(W1.y, x1, d1); a1 = fmaf(W1.z, x2, a1); d1 = fmaf(W1.w, x3, d1);
                        a2 = fmaf(W2.x, x0, a2); d2 = fmaf(W2.y, x1, d2); a2 = fmaf(W2.z, x2, a2); d2 = fmaf(W2.w, x3, d2);
                        a3 = fmaf(W3.x, x0, a3); d3 = fmaf(W3.y, x1, d3); a3 = fmaf(W3.z, x2, a3); d3 = fmaf(W3.w, x3, d3);
                    }
                }
            }
            float* p = part + ((s * 32 + b) * 2 + jq) * 4;
            p[0] = a0 + d0; p[1] = a1 + d1; p[2] = a2 + d2; p[3] = a3 + d3;
        }
        __syncthreads();

        // ---------- gate reduce + nonlinearity ----------
        if (tid < 256) {
            const int b = tid & 31, gate = (tid >> 5) & 3, jq = tid >> 7;
            const int j = blk * 2 + jq;
            float g = 0.f;
            #pragma unroll
            for (int s = 0; s < 8; ++s) g += part[((s * 32 + b) * 2 + jq) * 4 + gate];
            g += b_ih[gate * HIDDEN + j] + b_hh[gate * HIDDEN + j];
            gate_s[(jq * 4 + gate) * 32 + b] = (gate == 2) ? tanhf(g) : 1.f / (1.f + expf(-g));
        }
        __syncthreads();

        // ---------- cell update (c in registers) ----------
        if (tid < 64) {
            const int b = tid & 31, jq = tid >> 5;
            const int j = blk * 2 + jq;
            const float iv = gate_s[(jq * 4 + 0) * 32 + b], fv = gate_s[(jq * 4 + 1) * 32 + b];
            const float gv = gate_s[(jq * 4 + 2) * 32 + b], ov = gate_s[(jq * 4 + 3) * 32 + b];
            float cn = fv * c_reg + iv * gv;
            c_reg = cn;
            float hv = ov * tanhf(cn);
            const size_t ho = (size_t)widx * BATCH * HIDDEN + (size_t)b * HIDDEN + j;
            unsigned short hh = f2bf(hv);
            h_hi[ho] = hh;
            h_lo[ho] = f2bf(hv - bf2f(hh));
        }
        __syncthreads();

        // ---------- signal1: h(t) published (256 signalers, relaxed tree) ----------
        if (tid == 0) {
            __threadfence();
            const int leaf = blk >> 3;
            if (__hip_atomic_fetch_add(&s1[leaf], 1u, __ATOMIC_RELAXED, __HIP_MEMORY_SCOPE_AGENT) == 7u)
                __hip_atomic_fetch_add(&s1[32], 1u, __ATOMIC_RELAXED, __HIP_MEMORY_SCOPE_AGENT);
        }

        // ---------- phase G (blocks 0..249) ----------
        if (blk < GBLK) {
            const int w = tid >> 6, lane = tid & 63, row = lane & 15, kg = lane >> 4;
            const int vwave = blk * VB + w * 16;
            const unsigned short* wl = Wlo + (size_t)(vwave + row) * HIDDEN + kg * 8;

            // issue W_lo prefetch + bias BEFORE the wait (addresses independent of h)
            bf16x8 wlb[4];
            #pragma unroll
            for (int p = 0; p < 4; ++p) wlb[p] = *(const bf16x8*)(wl + p * 32);
            const int v4 = vwave + kg * 4;
            f32x4 bias = *(const f32x4*)(b_fc + v4);
            __builtin_amdgcn_sched_barrier(0);

            if (tid == 0) {
                while (__hip_atomic_load(&s1[32], __ATOMIC_RELAXED, __HIP_MEMORY_SCOPE_AGENT) != 32u)
                    __builtin_amdgcn_s_sleep(4);
                __threadfence();
            }
            __syncthreads();

            const unsigned short* hhw = h_hi + (size_t)widx * BATCH * HIDDEN;
            const unsigned short* hlw = h_lo + (size_t)widx * BATCH * HIDDEN;
            const int wr = w * 16 + row;

            f32x4 acc0 = {0.f, 0.f, 0.f, 0.f};   // b = row
            f32x4 acc1 = {0.f, 0.f, 0.f, 0.f};   // b = row + 16
            #pragma unroll
            for (int c = 0; c < 16; ++c) {
                bf16x8 cwl = wlb[c & 3];
                bf16x8 wh  = *WSPTR(wr, c);
                bf16x8 hh0 = *(const bf16x8*)(hhw + (size_t)row * HIDDEN + c * 32 + kg * 8);
                bf16x8 hh1 = *(const bf16x8*)(hhw + (size_t)(row + 16) * HIDDEN + c * 32 + kg * 8);
                bf16x8 hl0 = *(const bf16x8*)(hlw + (size_t)row * HIDDEN + c * 32 + kg * 8);
                bf16x8 hl1 = *(const bf16x8*)(hlw + (size_t)(row + 16) * HIDDEN + c * 32 + kg * 8);
                if (c + 4 < 16) wlb[c & 3] = *(const bf16x8*)(wl + (c + 4) * 32);
                acc0 = MFMA(wh, hh0, acc0);  acc1 = MFMA(wh, hh1, acc1);
                acc0 = MFMA(cwl, hh0, acc0); acc1 = MFMA(cwl, hh1, acc1);
                acc0 = MFMA(wh, hl0, acc0);  acc1 = MFMA(wh, hl1, acc1);
            }

            f32x4 st0, st1;
            unsigned long long best0 = 0ull, best1 = 0ull;
            #pragma unroll
            for (int jj = 0; jj < 4; ++jj) {
                st0[jj] = acc0[jj] + bias[jj];
                st1[jj] = acc1[jj] + bias[jj];
                unsigned long long e0 = ((unsigned long long)f32_ordered_key(st0[jj]) << 32)
                                      | (unsigned long long)(~(unsigned int)(v4 + jj));
                unsigned long long e1 = ((unsigned long long)f32_ordered_key(st1[jj]) << 32)
                                      | (unsigned long long)(~(unsigned int)(v4 + jj));
                if (e0 > best0) best0 = e0;
                if (e1 > best1) best1 = e1;
            }
            __builtin_nontemporal_store(st0, (f32x4*)(out + ((size_t)row * MAXLEN + t) * VOCAB + v4));
            __builtin_nontemporal_store(st1, (f32x4*)(out + ((size_t)(row + 16) * MAXLEN + t) * VOCAB + v4));

            #pragma unroll
            for (int sft = 16; sft <= 32; sft <<= 1) {
                unsigned long long o0 = __shfl_xor(best0, sft, 64);
                unsigned long long o1 = __shfl_xor(best1, sft, 64);
                if (o0 > best0) best0 = o0;
                if (o1 > best1) best1 = o1;
            }
            if (kg == 0) { red[w][row] = best0; red[w][row + 16] = best1; }
            __syncthreads();
            if (tid < BATCH) {
                unsigned long long m = red[0][tid];
                #pragma unroll
                for (int ww = 1; ww < 8; ++ww) if (red[ww][tid] > m) m = red[ww][tid];
                cand[(size_t)blk * BATCH + tid] = m;
            }
            __syncthreads();
        }

        // ---------- signal2 + wait2: cand(t) published (250 signalers) ----------
        if (t < MAXLEN - 1) {
            if (tid == 0 && blk < GBLK) {
                __threadfence();
                const int leaf = blk >> 3;
                const unsigned exp = (leaf == 31) ? 2u : 8u;
                if (__hip_atomic_fetch_add(&s2[leaf], 1u, __ATOMIC_RELAXED, __HIP_MEMORY_SCOPE_AGENT) == exp - 1u)
                    __hip_atomic_fetch_add(&s2[32], 1u, __ATOMIC_RELAXED, __HIP_MEMORY_SCOPE_AGENT);
            }
            if (tid == 0) {
                while (__hip_atomic_load(&s2[32], __ATOMIC_RELAXED, __HIP_MEMORY_SCOPE_AGENT) != 32u)
                    __builtin_amdgcn_s_sleep(4);
                __threadfence();
            }
            __syncthreads();
        }
    }
}

extern "C" void kernel_launch(void* const* d_in, const int* in_sizes, int n_in,
                              void* d_out, int out_size, void* d_ws, size_t ws_size,
                              hipStream_t stream) {
    const float* embed = (const float*)d_in[1];
    const float* W_ih  = (const float*)d_in[2];
    const float* W_hh  = (const float*)d_in[3];
    const float* b_ih  = (const float*)d_in[4];
    const float* b_hh  = (const float*)d_in[5];
    const float* W_fc  = (const float*)d_in[6];
    const float* b_fc  = (const float*)d_in[7];
    float* out = (float*)d_out;

    char* ws = (char*)d_ws;
    unsigned short* h_hi = (unsigned short*)(ws + WS_HHI_OFF);
    unsigned short* h_lo = (unsigned short*)(ws + WS_HLO_OFF);
    unsigned long long* cand = (unsigned long long*)(ws + WS_CAND_OFF);
    unsigned* stepctr = (unsigned*)(ws + WS_CTR_OFF);
    unsigned short* W_hi = (unsigned short*)(ws + WS_WHI_OFF);
    unsigned short* W_lo = (unsigned short*)(ws + WS_WLO_OFF);

    hipMemsetAsync(d_ws, 0, WS_ZERO_BYTES, stream);
    split_w_kernel<<<2048, 256, 0, stream>>>(W_fc, W_hi, W_lo, VOCAB * HIDDEN / 4);
    decoder_kernel<<<NBLK, 512, 0, stream>>>(
        embed, W_ih, W_hh, b_ih, b_hh, W_hi, W_lo, b_fc, out,
        h_hi, h_lo, cand, stepctr);
}

// Round 10
// 4477.740 us; speedup vs baseline: 2.5559x; 2.5559x over previous
//
#include <hip/hip_runtime.h>
#include <hip/hip_bf16.h>
#include <math.h>

#define VOCAB  32000
#define EMBED  256
#define HIDDEN 512
#define BATCH  32
#define MAXLEN 128
#define NCAND  250            // logits blocks = argmax candidates per b
#define VB     128            // v-rows per logits block

typedef __attribute__((ext_vector_type(8))) short bf16x8;          // 8 bf16 = 4 VGPR
typedef __attribute__((ext_vector_type(8))) unsigned short ushort8;
typedef __attribute__((ext_vector_type(4))) float f32x4;

// -------- workspace layout (bytes) --------
#define WS_C_OFF     0          // c[32][512] f32                    65536
#define WS_HHI_OFF   65536      // h_hi[2][32][512] bf16             65536
#define WS_HLO_OFF   131072     // h_lo[2][32][512] bf16             65536
#define WS_CAND_OFF  196608     // cand[250][32] u64                 64000
#define WS_WHI_OFF   260608     // W_hi[32000][512] bf16          32768000
#define WS_WLO_OFF   33028608   // W_lo[32000][512] bf16          32768000
#define WS_ZERO_BYTES 196608    // c + both h parities must start 0

__device__ __forceinline__ unsigned int f32_ordered_key(float f) {
    unsigned int b = __float_as_uint(f);
    return (b & 0x80000000u) ? ~b : (b | 0x80000000u);
}
__device__ __forceinline__ unsigned short f2bf(float x) {
    __hip_bfloat16 h = __float2bfloat16(x);
    return *reinterpret_cast<unsigned short*>(&h);
}
__device__ __forceinline__ float bf2f(unsigned short u) {
    __hip_bfloat16 h = *reinterpret_cast<__hip_bfloat16*>(&u);
    return __bfloat162float(h);
}

// ---------------- W_fc bf16 split precompute (once per launch) ----------------
__global__ __launch_bounds__(256) void split_w_kernel(
    const float* __restrict__ W, unsigned short* __restrict__ hi,
    unsigned short* __restrict__ lo, int n4)
{
    const int stride = gridDim.x * blockDim.x;
    for (int i = blockIdx.x * blockDim.x + threadIdx.x; i < n4; i += stride) {
        f32x4 w = ((const f32x4*)W)[i];
        ushort4 hv, lv;
        #pragma unroll
        for (int j = 0; j < 4; ++j) {
            float x = w[j];
            unsigned short hb = f2bf(x);
            ((unsigned short*)&hv)[j] = hb;
            ((unsigned short*)&lv)[j] = f2bf(x - bf2f(hb));
        }
        ((ushort4*)hi)[i] = hv;
        ((ushort4*)lo)[i] = lv;
    }
}

// ---------------- Kernel A: argmax-reduce + gather + gates + LSTM cell ----------------
// grid 256 x 256 threads. block handles j = blk*2 + {0,1} (all 4 gates, all 32 b).
__global__ __launch_bounds__(256) void lstm_step_kernel(
    const float* __restrict__ embed,
    const float* __restrict__ W_ih, const float* __restrict__ W_hh,
    const float* __restrict__ b_ih, const float* __restrict__ b_hh,
    const unsigned long long* __restrict__ cand,
    const unsigned short* __restrict__ hhi_prev, const unsigned short* __restrict__ hlo_prev,
    unsigned short* __restrict__ hhi_next, unsigned short* __restrict__ hlo_next,
    float* __restrict__ c_buf, int t)
{
    __shared__ float x_t[EMBED][33];    // transposed, padded: x_t[e][b]
    __shared__ float h_t[HIDDEN][33];   // transposed, padded: h_t[k][b]
    __shared__ int   tok_s[BATCH];
    __shared__ unsigned long long credl[8][BATCH];
    __shared__ float part[2][4][BATCH][4];   // [jp][s][b][gate]
    __shared__ float gate_s[2][4][BATCH];    // [jp][gate][b]

    const int tid = threadIdx.x;

    // ---- argmax reduce over 250 candidates per batch row ----
    if (t > 0) {
        const int rb = tid & 31, seg = tid >> 5;
        unsigned long long m = 0ull;
        for (int i = seg; i < NCAND; i += 8) {
            unsigned long long e = cand[(size_t)i * BATCH + rb];
            if (e > m) m = e;
        }
        credl[seg][rb] = m;
        __syncthreads();
        if (tid < BATCH) {
            unsigned long long mm = credl[0][tid];
            #pragma unroll
            for (int ss = 1; ss < 8; ++ss) if (credl[ss][tid] > mm) mm = credl[ss][tid];
            tok_s[tid] = (int)(~(unsigned int)(mm & 0xFFFFFFFFull));
        }
    } else {
        if (tid < BATCH) tok_s[tid] = 0;
    }
    __syncthreads();

    // ---- stage x (gather) and h (reconstruct hi+lo) transposed into LDS ----
    {
        const int sb = tid >> 3, slot = tid & 7;
        const float* er = embed + (size_t)tok_s[sb] * EMBED;
        #pragma unroll
        for (int i = 0; i < 8; ++i) {
            int e4 = i * 8 + slot;
            float4 v = ((const float4*)er)[e4];
            int e = e4 * 4;
            x_t[e + 0][sb] = v.x; x_t[e + 1][sb] = v.y;
            x_t[e + 2][sb] = v.z; x_t[e + 3][sb] = v.w;
        }
        const ushort8* hr = (const ushort8*)(hhi_prev + (size_t)sb * HIDDEN);
        const ushort8* lr = (const ushort8*)(hlo_prev + (size_t)sb * HIDDEN);
        #pragma unroll
        for (int i = 0; i < 8; ++i) {
            int u = i * 8 + slot;
            ushort8 hv = hr[u], lv = lr[u];
            #pragma unroll
            for (int e = 0; e < 8; ++e)
                h_t[u * 8 + e][sb] = bf2f((unsigned short)hv[e]) + bf2f((unsigned short)lv[e]);
        }
    }
    __syncthreads();

    // ---- gates partial dot products ----
    const int b  = tid & 31;
    const int s  = (tid >> 5) & 3;
    const int jp = tid >> 7;
    const int j  = blockIdx.x * 2 + jp;

    float a0 = 0.f, a1 = 0.f, a2 = 0.f, a3 = 0.f;
    float d0 = 0.f, d1 = 0.f, d2 = 0.f, d3 = 0.f;

    {   // x part: e in [s*64, s*64+64)
        const float4* w0 = (const float4*)(W_ih + (size_t)j * EMBED) + s * 16;
        const float4* w1 = (const float4*)(W_ih + (size_t)(HIDDEN + j) * EMBED) + s * 16;
        const float4* w2 = (const float4*)(W_ih + (size_t)(2 * HIDDEN + j) * EMBED) + s * 16;
        const float4* w3 = (const float4*)(W_ih + (size_t)(3 * HIDDEN + j) * EMBED) + s * 16;
        #pragma unroll 4
        for (int g = 0; g < 16; ++g) {
            float4 W0 = w0[g], W1 = w1[g], W2 = w2[g], W3 = w3[g];
            int e = s * 64 + g * 4;
            float x0 = x_t[e + 0][b], x1 = x_t[e + 1][b], x2 = x_t[e + 2][b], x3 = x_t[e + 3][b];
            a0 = fmaf(W0.x, x0, a0); d0 = fmaf(W0.y, x1, d0); a0 = fmaf(W0.z, x2, a0); d0 = fmaf(W0.w, x3, d0);
            a1 = fmaf(W1.x, x0, a1); d1 = fmaf(W1.y, x1, d1); a1 = fmaf(W1.z, x2, a1); d1 = fmaf(W1.w, x3, d1);
            a2 = fmaf(W2.x, x0, a2); d2 = fmaf(W2.y, x1, d2); a2 = fmaf(W2.z, x2, a2); d2 = fmaf(W2.w, x3, d2);
            a3 = fmaf(W3.x, x0, a3); d3 = fmaf(W3.y, x1, d3); a3 = fmaf(W3.z, x2, a3); d3 = fmaf(W3.w, x3, d3);
        }
    }
    {   // h part: k in [s*128, s*128+128)
        const float4* w0 = (const float4*)(W_hh + (size_t)j * HIDDEN) + s * 32;
        const float4* w1 = (const float4*)(W_hh + (size_t)(HIDDEN + j) * HIDDEN) + s * 32;
        const float4* w2 = (const float4*)(W_hh + (size_t)(2 * HIDDEN + j) * HIDDEN) + s * 32;
        const float4* w3 = (const float4*)(W_hh + (size_t)(3 * HIDDEN + j) * HIDDEN) + s * 32;
        #pragma unroll 4
        for (int g = 0; g < 32; ++g) {
            float4 W0 = w0[g], W1 = w1[g], W2 = w2[g], W3 = w3[g];
            int k = s * 128 + g * 4;
            float x0 = h_t[k + 0][b], x1 = h_t[k + 1][b], x2 = h_t[k + 2][b], x3 = h_t[k + 3][b];
            a0 = fmaf(W0.x, x0, a0); d0 = fmaf(W0.y, x1, d0); a0 = fmaf(W0.z, x2, a0); d0 = fmaf(W0.w, x3, d0);
            a1 = fmaf(W1.x, x0, a1); d1 = fmaf(W1.y, x1, d1); a1 = fmaf(W1.z, x2, a1); d1 = fmaf(W1.w, x3, d1);
            a2 = fmaf(W2.x, x0, a2); d2 = fmaf(W2.y, x1, d2); a2 = fmaf(W2.z, x2, a2); d2 = fmaf(W2.w, x3, d2);
            a3 = fmaf(W3.x, x0, a3); d3 = fmaf(W3.y, x1, d3); a3 = fmaf(W3.z, x2, a3); d3 = fmaf(W3.w, x3, d3);
        }
    }
    part[jp][s][b][0] = a0 + d0;
    part[jp][s][b][1] = a1 + d1;
    part[jp][s][b][2] = a2 + d2;
    part[jp][s][b][3] = a3 + d3;
    __syncthreads();

    // ---- gate reduce + nonlinearity (256 threads = 2j x 4gate x 32b) ----
    {
        const int gb = tid & 31, gate = (tid >> 5) & 3, gjp = tid >> 7;
        const int jj = blockIdx.x * 2 + gjp;
        float g = part[gjp][0][gb][gate] + part[gjp][1][gb][gate]
                + part[gjp][2][gb][gate] + part[gjp][3][gb][gate];
        g += b_ih[gate * HIDDEN + jj] + b_hh[gate * HIDDEN + jj];
        gate_s[gjp][gate][gb] = (gate == 2) ? tanhf(g) : 1.f / (1.f + expf(-g));
    }
    __syncthreads();

    // ---- cell update (64 threads) ----
    if (tid < 64) {
        const int cb = tid & 31, cjp = tid >> 5;
        const int jj = blockIdx.x * 2 + cjp;
        const float iv = gate_s[cjp][0][cb], fv = gate_s[cjp][1][cb];
        const float gv = gate_s[cjp][2][cb], ov = gate_s[cjp][3][cb];
        const size_t off = (size_t)cb * HIDDEN + jj;
        float cn = fv * c_buf[off] + iv * gv;
        c_buf[off] = cn;
        float hv = ov * tanhf(cn);
        unsigned short hh = f2bf(hv);
        hhi_next[off] = hh;
        hlo_next[off] = f2bf(hv - bf2f(hh));
    }
}

// ---------------- Kernel B (MFMA): logits GEMM + nt-store + per-block argmax ----------------
// grid 250 x 512 threads (8 waves). wave w: 16 v-rows x 32 b. h hi/lo staged in swizzled LDS.
// 3-pass split: Wh*Hh + Wl*Hh + Wh*Hl (lo*lo dropped, ~1e-7 contribution).
// W stream: depth-8 rotating register prefetch (16 KB/wave in flight; round-10 change).
#define MFMA(a, b, c) __builtin_amdgcn_mfma_f32_16x16x32_bf16((a), (b), (c), 0, 0, 0)
#define HPTR(arr, bb, cc) \
    ((const bf16x8*)((const char*)(arr) + ((((bb) * 1024) + (kg * 16) + (cc) * 64) ^ ((((bb) & 7)) << 4))))

__global__ __launch_bounds__(512) void logits_mfma_kernel(
    const unsigned short* __restrict__ Whi, const unsigned short* __restrict__ Wlo,
    const unsigned short* __restrict__ hhi, const unsigned short* __restrict__ hlo,
    const float* __restrict__ b_fc, float* __restrict__ out,
    unsigned long long* __restrict__ cand, int t)
{
    __shared__ unsigned short hs_hi[BATCH * HIDDEN];   // 32KB, XOR-swizzled rows
    __shared__ unsigned short hs_lo[BATCH * HIDDEN];   // 32KB
    __shared__ unsigned long long red[8][BATCH];

    const int tid = threadIdx.x;

    const int w    = tid >> 6;
    const int lane = tid & 63;
    const int row  = lane & 15;          // v-row within tile (A), also b for acc0 (B)
    const int kg   = lane >> 4;
    const int vwave = blockIdx.x * VB + w * 16;

    const unsigned short* wh = Whi + (size_t)(vwave + row) * HIDDEN + kg * 8;
    const unsigned short* wl = Wlo + (size_t)(vwave + row) * HIDDEN + kg * 8;

    // depth-8 rotating prefetch buffers (all indices static after full unroll);
    // issued FIRST so the W stream is in flight during h staging.
    bf16x8 whb[8], wlb[8];
    #pragma unroll
    for (int p = 0; p < 8; ++p) {
        whb[p] = *(const bf16x8*)(wh + p * 32);
        wlb[p] = *(const bf16x8*)(wl + p * 32);
    }

    // ---- stage h hi/lo into swizzled LDS (4096 16B units / 512 threads = 8 each) ----
    #pragma unroll
    for (int i = 0; i < 8; ++i) {
        int u   = i * 512 + tid;
        int arr = u >> 11;               // 0 = hi, 1 = lo
        int b   = (u >> 6) & 31;
        int k16 = u & 63;
        const unsigned short* src = (arr ? hlo : hhi) + (size_t)b * HIDDEN + k16 * 8;
        int4 v = *(const int4*)src;
        char* dst = (char*)(arr ? hs_lo : hs_hi) + ((b * 1024 + k16 * 16) ^ ((b & 7) << 4));
        *(int4*)dst = v;
    }
    __syncthreads();

    f32x4 acc0 = {0.f, 0.f, 0.f, 0.f};   // b = row
    f32x4 acc1 = {0.f, 0.f, 0.f, 0.f};   // b = row + 16

    #pragma unroll
    for (int c = 0; c < 16; ++c) {
        bf16x8 cwh = whb[c & 7], cwl = wlb[c & 7];
        bf16x8 hh0 = *HPTR(hs_hi, row, c),      hh1 = *HPTR(hs_hi, row + 16, c);
        bf16x8 hl0 = *HPTR(hs_lo, row, c),      hl1 = *HPTR(hs_lo, row + 16, c);
        if (c + 8 < 16) {
            whb[c & 7] = *(const bf16x8*)(wh + (c + 8) * 32);
            wlb[c & 7] = *(const bf16x8*)(wl + (c + 8) * 32);
        }
        acc0 = MFMA(cwh, hh0, acc0); acc1 = MFMA(cwh, hh1, acc1);
        acc0 = MFMA(cwl, hh0, acc0); acc1 = MFMA(cwl, hh1, acc1);
        acc0 = MFMA(cwh, hl0, acc0); acc1 = MFMA(cwh, hl1, acc1);
    }

    // ---- epilogue: bias + NT store + argmax candidates ----
    const int v4 = vwave + kg * 4;        // D: row(m) = kg*4 + reg -> v; col(n) = row -> b
    f32x4 bias = *(const f32x4*)(b_fc + v4);
    f32x4 st0, st1;
    unsigned long long best0 = 0ull, best1 = 0ull;
    #pragma unroll
    for (int jj = 0; jj < 4; ++jj) {
        st0[jj] = acc0[jj] + bias[jj];
        st1[jj] = acc1[jj] + bias[jj];
        unsigned long long e0 = ((unsigned long long)f32_ordered_key(st0[jj]) << 32)
                              | (unsigned long long)(~(unsigned int)(v4 + jj));
        unsigned long long e1 = ((unsigned long long)f32_ordered_key(st1[jj]) << 32)
                              | (unsigned long long)(~(unsigned int)(v4 + jj));
        if (e0 > best0) best0 = e0;
        if (e1 > best1) best1 = e1;
    }
    __builtin_nontemporal_store(st0, (f32x4*)(out + ((size_t)row * MAXLEN + t) * VOCAB + v4));
    __builtin_nontemporal_store(st1, (f32x4*)(out + ((size_t)(row + 16) * MAXLEN + t) * VOCAB + v4));

    #pragma unroll
    for (int sft = 16; sft <= 32; sft <<= 1) {
        unsigned long long o0 = __shfl_xor(best0, sft, 64);
        unsigned long long o1 = __shfl_xor(best1, sft, 64);
        if (o0 > best0) best0 = o0;
        if (o1 > best1) best1 = o1;
    }
    if (kg == 0) { red[w][row] = best0; red[w][row + 16] = best1; }
    __syncthreads();
    if (tid < BATCH) {
        unsigned long long m = red[0][tid];
        #pragma unroll
        for (int ww = 1; ww < 8; ++ww) if (red[ww][tid] > m) m = red[ww][tid];
        cand[(size_t)blockIdx.x * BATCH + tid] = m;   // plain store, no atomics
    }
}

extern "C" void kernel_launch(void* const* d_in, const int* in_sizes, int n_in,
                              void* d_out, int out_size, void* d_ws, size_t ws_size,
                              hipStream_t stream) {
    const float* embed = (const float*)d_in[1];
    const float* W_ih  = (const float*)d_in[2];
    const float* W_hh  = (const float*)d_in[3];
    const float* b_ih  = (const float*)d_in[4];
    const float* b_hh  = (const float*)d_in[5];
    const float* W_fc  = (const float*)d_in[6];
    const float* b_fc  = (const float*)d_in[7];
    float* out = (float*)d_out;

    char* ws = (char*)d_ws;
    float* c_buf = (float*)(ws + WS_C_OFF);
    unsigned short* h_hi = (unsigned short*)(ws + WS_HHI_OFF);   // [2][32][512]
    unsigned short* h_lo = (unsigned short*)(ws + WS_HLO_OFF);   // [2][32][512]
    unsigned long long* cand = (unsigned long long*)(ws + WS_CAND_OFF);
    unsigned short* W_hi = (unsigned short*)(ws + WS_WHI_OFF);
    unsigned short* W_lo = (unsigned short*)(ws + WS_WLO_OFF);

    hipMemsetAsync(d_ws, 0, WS_ZERO_BYTES, stream);
    split_w_kernel<<<2048, 256, 0, stream>>>(W_fc, W_hi, W_lo, VOCAB * HIDDEN / 4);

    for (int t = 0; t < MAXLEN; ++t) {
        const int p = t & 1;
        unsigned short* hhi_prev = h_hi + (size_t)p * BATCH * HIDDEN;
        unsigned short* hlo_prev = h_lo + (size_t)p * BATCH * HIDDEN;
        unsigned short* hhi_next = h_hi + (size_t)(p ^ 1) * BATCH * HIDDEN;
        unsigned short* hlo_next = h_lo + (size_t)(p ^ 1) * BATCH * HIDDEN;
        lstm_step_kernel<<<256, 256, 0, stream>>>(
            embed, W_ih, W_hh, b_ih, b_hh, cand,
            hhi_prev, hlo_prev, hhi_next, hlo_next, c_buf, t);
        logits_mfma_kernel<<<NCAND, 512, 0, stream>>>(
            W_hi, W_lo, hhi_next, hlo_next, b_fc, out, cand, t);
    }
}